// Round 12
// baseline (204.313 us; speedup 1.0000x reference)
//
#include <hip/hip_runtime.h>
#include <hip/hip_bf16.h>

#define NSEG 512
#define HID 768

typedef __attribute__((ext_vector_type(8))) short s16x8;
typedef __attribute__((ext_vector_type(8))) unsigned short u16x8;
typedef __attribute__((ext_vector_type(4))) unsigned short u16x4;
typedef __attribute__((ext_vector_type(4))) float f32x4;

__device__ __forceinline__ unsigned short f2bf(float x) {
  unsigned u = __builtin_bit_cast(unsigned, x);
  unsigned r = (u + 0x7fff + ((u >> 16) & 1)) >> 16;   // RNE
  return (unsigned short)r;
}

__device__ __forceinline__ float bf2f(unsigned short h) {
  unsigned u = ((unsigned)h) << 16;
  return __builtin_bit_cast(float, u);
}

__device__ __forceinline__ void gl_lds16(const void* g, void* l) {
  __builtin_amdgcn_global_load_lds(
      (const __attribute__((address_space(1))) unsigned*)g,
      (__attribute__((address_space(3))) unsigned*)l, 16, 0, 0);
}

// ---------------- fused compose (all chains) + histogram (all levels) ----------------
struct PreArgs {
  const int *inv1, *inv2, *inv3, *inv4;
  int *c20, *c31, *c30, *c42, *c41, *c40;
  const int* p2s[5];
  int* cnt;
};

__device__ __forceinline__ bool lvl_decode(int t, int& lvl, int& u, int& N) {
  if      (t < 512)    { lvl = 0; u = t;          N = 256; }
  else if (t < 2560)   { lvl = 1; u = t - 512;    N = 1024; }
  else if (t < 10752)  { lvl = 2; u = t - 2560;   N = 4096; }
  else if (t < 43520)  { lvl = 3; u = t - 10752;  N = 16384; }
  else if (t < 174592) { lvl = 4; u = t - 43520;  N = 65536; }
  else return false;
  return true;
}

__global__ __launch_bounds__(256)
void pre_k(PreArgs a) {
  int t = blockIdx.x * 256 + threadIdx.x;
  if (t < 8192) {
    int b = (t >= 4096);
    a.c20[t] = a.inv1[b * 1024 + a.inv2[t]];
  } else if (t < 40960) {
    int u = t - 8192;
    int b = (u >= 16384);
    int n2 = a.inv3[u];
    int n1 = a.inv2[b * 4096 + n2]; a.c31[u] = n1;
    a.c30[u] = a.inv1[b * 1024 + n1];
  } else if (t < 172032) {
    int u = t - 40960;
    int b = (u >= 65536);
    int n3 = a.inv4[u];
    int n2 = a.inv3[b * 16384 + n3]; a.c42[u] = n2;
    int n1 = a.inv2[b * 4096 + n2];  a.c41[u] = n1;
    a.c40[u] = a.inv1[b * 1024 + n1];
  } else {
    int u0 = t - 172032;
    int lvl, u, N;
    if (!lvl_decode(u0, lvl, u, N)) return;
    int b = (u >= N);
    atomicAdd(&a.cnt[lvl * 1024 + b * NSEG + a.p2s[lvl][u]], 1);
  }
}

// ---------------- scan + 1/m ----------------
__global__ __launch_bounds__(512)
void scan_k(const int* __restrict__ cnt, int* __restrict__ off, float* __restrict__ scl) {
  __shared__ int sm[NSEG];
  int base = blockIdx.x * NSEG;
  int t = threadIdx.x;
  int v = cnt[base + t];
  sm[t] = v;
  __syncthreads();
  for (int d = 1; d < NSEG; d <<= 1) {
    int u = (t >= d) ? sm[t - d] : 0;
    __syncthreads();
    sm[t] += u;
    __syncthreads();
  }
  off[base + t] = sm[t] - v;
  scl[base + t] = 1.0f / (float)(v > 0 ? v : 1);
}

// ---------------- fused scatter (all levels) ----------------
struct ScArgs { const int* p2s[5]; int* pt[5]; int* cur; const int* off; };

__global__ __launch_bounds__(256)
void scat_all_k(ScArgs a) {
  int t = blockIdx.x * 256 + threadIdx.x;
  int lvl, u, N;
  if (!lvl_decode(t, lvl, u, N)) return;
  int b = (u >= N);
  int n = u - b * N;
  int idx = lvl * 1024 + b * NSEG + a.p2s[lvl][u];
  int pos = a.off[idx] + atomicAdd(&a.cur[idx], 1);
  a.pt[lvl][b * N + pos] = n;
}

// ---------------- mega reduce, XCD-sliced for lvl3/4 upsampled blocks ----------------
// grid 22528:
//  [0,1024)      lvl0 direct (256-wide, 2 groups/thread)
//  [1024,2048)   lvl1 direct
//  [2048,4096)   lvl2 chunked (NC=2)
//  [4096,5120)   lvl3 NATIVE  (waves=chunks, lanes<24, ch [0,96))
//  [5120,6144)   lvl4 NATIVE  (waves=chunks, lanes<12, ch [0,48))
//  [6144,14336)  lvl3 SLICED  (slice=local&7, 34 groups contiguous, ch [96,1184))
//  [14336,22528) lvl4 SLICED  (slice=local&7, 37 groups contiguous, ch [48,1232))
// slice blocks share slice==gb%8 -> same XCD (round-robin dispatch heuristic;
// correctness independent of mapping). Waves act as point-chunks (chunk=wave).
struct RedAll {
  const float* x[5][5];
  const int*   ci[5][5];
  int Njl[5][5], CN[5][5], colOFF[5][5];
  int nb[5], N[5], CF[5], nchunk[5];
  const int* pt[5]; const int* cnt[5]; const int* segoff[5];
  float* seg01[2];
  unsigned short* part[5];
};

__global__ __launch_bounds__(256)
void reduce3_k(RedAll A) {
  int gb = blockIdx.x;

  if (gb < 4096) {
    // ---- full-width path (lvl 0,1,2) — r11 code unchanged ----
    int lvl, lb;
    if      (gb < 1024) { lvl = 0; lb = gb; }
    else if (gb < 2048) { lvl = 1; lb = gb - 1024; }
    else                { lvl = 2; lb = gb - 2048; }
    int chunk = lb >> 10;
    int bs    = lb & 1023;
    int b     = bs >> 9;
    int t     = threadIdx.x;
    int m     = A.cnt[lvl][bs];
    int CF    = A.CF[lvl];
    int nb    = A.nb[lvl];
    int N     = A.N[lvl];

    const float* xs[2]; const int* cim[2]; int str[2]; bool val[2];
#pragma unroll
    for (int k = 0; k < 2; k++) {
      int c4 = (t + k * 256) * 4;
      val[k] = c4 < CF;
      xs[k] = nullptr; cim[k] = nullptr; str[k] = 1;
      if (val[k]) {
        int j = 0;
        while (j < nb - 1 && !(c4 >= A.colOFF[lvl][j] && c4 < A.colOFF[lvl][j] + A.CN[lvl][j])) j++;
        xs[k]  = A.x[lvl][j] + (size_t)b * A.Njl[lvl][j] * A.CN[lvl][j] + (c4 - A.colOFF[lvl][j]);
        cim[k] = A.ci[lvl][j] ? (A.ci[lvl][j] + (size_t)b * N) : nullptr;
        str[k] = A.CN[lvl][j];
      }
    }

    bool direct = (lvl <= 1);
    int start = 0, end = m;
    if (!direct) {
      int nch = A.nchunk[lvl];
      int cs = (m + nch - 1) / nch;
      start = chunk * cs;
      end = min(m, start + cs);
    } else if (m == 0) {
      float* so = A.seg01[lvl] + (size_t)bs * CF;
#pragma unroll
      for (int k = 0; k < 2; k++)
        if (val[k]) *(float4*)(so + (t + k * 256) * 4) = make_float4(0.f, 0.f, 0.f, 0.f);
      return;
    }

    float ax[2][4] = {};
    if (start < end) {
      const int* pl = A.pt[lvl] + (size_t)b * N + A.segoff[lvl][bs];
      int p = start;
      for (; p + 8 <= end; p += 8) {
        int n[8];
#pragma unroll
        for (int q = 0; q < 8; q++) n[q] = pl[p + q];
#pragma unroll
        for (int k = 0; k < 2; k++) if (val[k]) {
          int r[8];
#pragma unroll
          for (int q = 0; q < 8; q++) r[q] = cim[k] ? cim[k][n[q]] : n[q];
          float4 v[8];
#pragma unroll
          for (int q = 0; q < 8; q++) v[q] = *(const float4*)(xs[k] + (size_t)r[q] * str[k]);
#pragma unroll
          for (int q = 0; q < 8; q++) {
            ax[k][0] += v[q].x; ax[k][1] += v[q].y; ax[k][2] += v[q].z; ax[k][3] += v[q].w;
          }
        }
      }
      for (; p < end; p++) {
        int n0 = pl[p];
#pragma unroll
        for (int k = 0; k < 2; k++) if (val[k]) {
          int r0 = cim[k] ? cim[k][n0] : n0;
          float4 v0 = *(const float4*)(xs[k] + (size_t)r0 * str[k]);
          ax[k][0] += v0.x; ax[k][1] += v0.y; ax[k][2] += v0.z; ax[k][3] += v0.w;
        }
      }
    }

    if (direct) {
      float* so = A.seg01[lvl] + (size_t)bs * CF;
#pragma unroll
      for (int k = 0; k < 2; k++) if (val[k]) {
        int c4 = (t + k * 256) * 4;
        *(float4*)(so + c4) = make_float4(ax[k][0], ax[k][1], ax[k][2], ax[k][3]);
      }
    } else {
      unsigned short* po = A.part[lvl] + ((size_t)chunk * 1024 + bs) * CF;
#pragma unroll
      for (int k = 0; k < 2; k++) if (val[k]) {
        int c4 = (t + k * 256) * 4;
        u16x4 o = {f2bf(ax[k][0]), f2bf(ax[k][1]), f2bf(ax[k][2]), f2bf(ax[k][3])};
        *(u16x4*)(po + c4) = o;
      }
    }
    return;
  }

  // ---- thin path (lvl 3/4 native + sliced); wave = point-chunk ----
  int lvl, bs, gbase, gcnt;
  if (gb < 5120)       { lvl = 3; bs = gb - 4096; gbase = 0; gcnt = 24; }
  else if (gb < 6144)  { lvl = 4; bs = gb - 5120; gbase = 0; gcnt = 12; }
  else if (gb < 14336) { int l = gb - 6144;  lvl = 3; bs = l >> 3; gbase = 24 + 34 * (l & 7); gcnt = 34; }
  else                 { int l = gb - 14336; lvl = 4; bs = l >> 3; gbase = 12 + 37 * (l & 7); gcnt = 37; }

  int wave = threadIdx.x >> 6;
  int lane = threadIdx.x & 63;
  int NC = A.nchunk[lvl];
  if (wave >= NC) return;
  int m  = A.cnt[lvl][bs];
  int b  = bs >> 9;
  int N  = A.N[lvl];
  int CF = A.CF[lvl];

  bool val = lane < gcnt;
  int c4 = (gbase + lane) * 4;
  const float* xs = nullptr; const int* cim = nullptr; int str = 1;
  if (val) {
    int nb = A.nb[lvl];
    int j = 0;
    while (j < nb - 1 && !(c4 >= A.colOFF[lvl][j] && c4 < A.colOFF[lvl][j] + A.CN[lvl][j])) j++;
    xs  = A.x[lvl][j] + (size_t)b * A.Njl[lvl][j] * A.CN[lvl][j] + (c4 - A.colOFF[lvl][j]);
    cim = A.ci[lvl][j] ? (A.ci[lvl][j] + (size_t)b * N) : nullptr;
    str = A.CN[lvl][j];
  }

  int cs = (m + NC - 1) / NC;
  int start = wave * cs;
  int end = min(m, start + cs);

  float a0 = 0.f, a1 = 0.f, a2 = 0.f, a3 = 0.f;
  if (val && start < end) {
    const int* pl = A.pt[lvl] + (size_t)b * N + A.segoff[lvl][bs];
    int p = start;
    for (; p + 8 <= end; p += 8) {
      int n[8];
#pragma unroll
      for (int q = 0; q < 8; q++) n[q] = pl[p + q];
      int r[8];
#pragma unroll
      for (int q = 0; q < 8; q++) r[q] = cim ? cim[n[q]] : n[q];
      float4 v[8];
#pragma unroll
      for (int q = 0; q < 8; q++) v[q] = *(const float4*)(xs + (size_t)r[q] * str);
#pragma unroll
      for (int q = 0; q < 8; q++) {
        a0 += v[q].x; a1 += v[q].y; a2 += v[q].z; a3 += v[q].w;
      }
    }
    for (; p < end; p++) {
      int n0 = pl[p];
      int r0 = cim ? cim[n0] : n0;
      float4 v0 = *(const float4*)(xs + (size_t)r0 * str);
      a0 += v0.x; a1 += v0.y; a2 += v0.z; a3 += v0.w;
    }
  }

  if (val) {
    unsigned short* po = A.part[lvl] + ((size_t)wave * 1024 + bs) * CF + c4;
    u16x4 o = {f2bf(a0), f2bf(a1), f2bf(a2), f2bf(a3)};
    *(u16x4*)po = o;
  }
}

// ---------------- combine partials + scale + bf16 + chunk-swizzle + K-pad ----------------
struct CsArgs {
  const float* sg[2];
  const unsigned short* pp[5];
  unsigned short* sb[5];
  const float* scl;
  int CF[5]; int KP[5]; int NC[5];
};

__global__ __launch_bounds__(256)
void conv_seg_k(CsArgs a) {
  int row = blockIdx.x;            // 0..5119
  int lvl = row >> 10;
  int rl  = row & 1023;
  int CF = a.CF[lvl], KP = a.KP[lvl];
  int c = threadIdx.x;
  if (c >= (KP >> 3)) return;
  float s = a.scl[row];
  int w = c & 7, blk = c >> 3;
  int k0 = blk * 64 + ((w ^ (rl & 7)) << 3);
  u16x8 o = {0, 0, 0, 0, 0, 0, 0, 0};
  if (k0 < CF) {
    float acc[8] = {};
    if (lvl <= 1) {
      const float* src = a.sg[lvl] + (size_t)rl * CF + k0;
      float4 v0 = *(const float4*)src;
      float4 v1 = *(const float4*)(src + 4);
      acc[0] = v0.x; acc[1] = v0.y; acc[2] = v0.z; acc[3] = v0.w;
      acc[4] = v1.x; acc[5] = v1.y; acc[6] = v1.z; acc[7] = v1.w;
    } else {
      int nc = a.NC[lvl];
      const unsigned short* base = a.pp[lvl] + (size_t)rl * CF + k0;
      for (int n = 0; n < nc; n++) {
        u16x8 v = *(const u16x8*)(base + (size_t)n * 1024 * CF);
#pragma unroll
        for (int e = 0; e < 8; e++) acc[e] += bf2f(v[e]);
      }
    }
#pragma unroll
    for (int e = 0; e < 8; e++) o[e] = f2bf(acc[e] * s);
  }
  *(u16x8*)(a.sb[lvl] + (size_t)rl * KP + c * 8) = o;
}

// ---------------- W -> Wt bf16 transposed+swizzled via LDS tiles ----------------
struct CwArgs { const float* w[5]; unsigned short* wt[5]; int CF[5]; int KP[5]; };

__global__ __launch_bounds__(256)
void conv_wtt_k(CwArgs a) {
  int lvl = blockIdx.y;
  int KP = a.KP[lvl], CF = a.CF[lvl];
  int ntiles = 12 * (KP >> 6);
  int tile = blockIdx.x;
  if (tile >= ntiles) return;
  int kb  = tile / 12;
  int nb0 = tile - kb * 12;
  int t = threadIdx.x;

  __shared__ float lds[64][65];

  const float* wsrc = a.w[lvl];
#pragma unroll
  for (int e = 0; e < 4; e++) {
    int f = e * 256 + t;
    int row = f >> 4;
    int c4  = (f & 15) * 4;
    int k = kb * 64 + row;
    float4 v = make_float4(0.f, 0.f, 0.f, 0.f);
    if (k < CF) v = *(const float4*)(wsrc + (size_t)k * HID + nb0 * 64 + c4);
    lds[row][c4 + 0] = v.x; lds[row][c4 + 1] = v.y;
    lds[row][c4 + 2] = v.z; lds[row][c4 + 3] = v.w;
  }
  __syncthreads();

  unsigned short* wt = a.wt[lvl];
#pragma unroll
  for (int h = 0; h < 2; h++) {
    int idx2 = h * 256 + t;
    int n_loc = idx2 >> 3;
    int w2    = idx2 & 7;
    int kbase = (w2 ^ (n_loc & 7)) << 3;
    u16x8 o;
#pragma unroll
    for (int e = 0; e < 8; e++) o[e] = f2bf(lds[kbase + e][n_loc]);
    int n = nb0 * 64 + n_loc;
    *(u16x8*)(wt + (size_t)n * KP + kb * 64 + w2 * 8) = o;
  }
}

// ---------------- bf16 MFMA GEMM: proj = segbf @ Wt^T + bias ----------------
struct G2Args {
  const unsigned short* sb[5];
  const unsigned short* wt[5];
  const float* bias[5];
  float* proj;
  int KP[5];
  int KIT[5];
};

__global__ __launch_bounds__(256)
void gemm2_k(G2Args g) {
  int lvl = blockIdx.z;
  int n0 = blockIdx.x * 64;
  int m0 = blockIdx.y * 128;
  const char* A = (const char*)g.sb[lvl];
  const char* Bw = (const char*)g.wt[lvl];
  int KP = g.KP[lvl];
  int KIT = g.KIT[lvl];

  __shared__ char smem[49152];

  int t = threadIdx.x;
  int lane = t & 63;
  int w = t >> 6;
  int wm = w >> 1, wn = w & 1;

  f32x4 acc[4][2] = {};

  int rowb = t >> 3;
  int colb = (t & 7) * 16;

  auto stg = [&](int buf, int it) {
    char* base = smem + buf * 24576;
#pragma unroll
    for (int j = 0; j < 4; j++) {
      int row = j * 32 + rowb;
      gl_lds16(A + (size_t)(m0 + row) * (KP * 2) + it * 128 + colb,
               base + j * 4096 + t * 16);
    }
#pragma unroll
    for (int j = 0; j < 2; j++) {
      int row = j * 32 + rowb;
      gl_lds16(Bw + (size_t)(n0 + row) * (KP * 2) + it * 128 + colb,
               base + 16384 + j * 4096 + t * 16);
    }
  };

  int r15 = lane & 15, hi = lane >> 4, sx = (lane & 7) << 4;

  stg(0, 0);
  int cur = 0;
  for (int it = 0; it < KIT; ++it) {
    __syncthreads();
    if (it + 1 < KIT) stg(cur ^ 1, it + 1);
    const char* base = smem + cur * 24576;
    s16x8 af[2][4]; s16x8 bf2v[2][2];
#pragma unroll
    for (int s = 0; s < 2; s++) {
      int cb = (s * 64 + hi * 16) ^ sx;
#pragma unroll
      for (int fm = 0; fm < 4; fm++) {
        int row = wm * 64 + fm * 16 + r15;
        af[s][fm] = *(const s16x8*)(base + row * 128 + cb);
      }
#pragma unroll
      for (int fn = 0; fn < 2; fn++) {
        int row = wn * 32 + fn * 16 + r15;
        bf2v[s][fn] = *(const s16x8*)(base + 16384 + row * 128 + cb);
      }
    }
#pragma unroll
    for (int s = 0; s < 2; s++)
#pragma unroll
      for (int fm = 0; fm < 4; fm++)
#pragma unroll
        for (int fn = 0; fn < 2; fn++)
          acc[fm][fn] = __builtin_amdgcn_mfma_f32_16x16x32_bf16(af[s][fm], bf2v[s][fn], acc[fm][fn], 0, 0, 0);
    cur ^= 1;
  }

  const float* bias = g.bias[lvl];
  float* proj = g.proj + ((size_t)lvl * 1024 + m0) * HID;
#pragma unroll
  for (int fm = 0; fm < 4; fm++)
#pragma unroll
    for (int fn = 0; fn < 2; fn++) {
      int col = n0 + wn * 32 + fn * 16 + r15;
      int rb = wm * 64 + fm * 16 + hi * 4;
      float bi = bias[col];
      f32x4 v = acc[fm][fn];
#pragma unroll
      for (int r = 0; r < 4; r++)
        proj[(size_t)(rb + r) * HID + col] = v[r] + bi;
    }
}

// ---------------- LayerNorm over HID=768 (fp32 in/out) ----------------
struct LnArgs { const float* g[5]; const float* be[5]; };

__global__ __launch_bounds__(256)
void ln_k(LnArgs la, const float* __restrict__ proj, float* __restrict__ out) {
  int row = blockIdx.x;
  int lvl = row >> 10;
  const float* x = proj + (size_t)row * HID;
  int t = threadIdx.x;
  float v0 = x[t], v1 = x[t + 256], v2 = x[t + 512];
  float s = v0 + v1 + v2;
  float q = v0 * v0 + v1 * v1 + v2 * v2;
#pragma unroll
  for (int d = 32; d >= 1; d >>= 1) { s += __shfl_down(s, d); q += __shfl_down(q, d); }
  __shared__ float ps[4], pq[4];
  int w = t >> 6;
  if ((t & 63) == 0) { ps[w] = s; pq[w] = q; }
  __syncthreads();
  float S = ps[0] + ps[1] + ps[2] + ps[3];
  float Q = pq[0] + pq[1] + pq[2] + pq[3];
  float mean = S * (1.0f / HID);
  float var  = Q * (1.0f / HID) - mean * mean;
  float rs   = rsqrtf(var + 1e-5f);
  const float* g  = la.g[lvl];
  const float* be = la.be[lvl];
  float* o = out + (size_t)row * HID;
  o[t]       = (v0 - mean) * rs * g[t]       + be[t];
  o[t + 256] = (v1 - mean) * rs * g[t + 256] + be[t + 256];
  o[t + 512] = (v2 - mean) * rs * g[t + 512] + be[t + 512];
}

// =====================================================================
extern "C" void kernel_launch(void* const* d_in, const int* in_sizes, int n_in,
                              void* d_out, int out_size, void* d_ws, size_t ws_size,
                              hipStream_t stream) {
  static const int N_[5]  = {256, 1024, 4096, 16384, 65536};
  static const int CN_[5] = {512, 384, 192, 96, 48};
  static const int CF_[5] = {512, 896, 1088, 1184, 1232};
  static const int KP_[5] = {512, 896, 1088, 1216, 1280};   // CF rounded to 64
  static const int NC_[5] = {1, 1, 2, 2, 4};                // point-chunks (no atomics)

  const float* x[5]; const int* p2s[5]; const float* W[5];
  const float* bias[5]; const float* g[5]; const float* be[5];
  for (int i = 0; i < 5; i++) {
    x[i]    = (const float*)d_in[6 * i + 0];
    p2s[i]  = (const int*)  d_in[6 * i + 1];
    W[i]    = (const float*)d_in[6 * i + 2];
    bias[i] = (const float*)d_in[6 * i + 3];
    g[i]    = (const float*)d_in[6 * i + 4];
    be[i]   = (const float*)d_in[6 * i + 5];
  }
  const int* inv[5] = {nullptr, (const int*)d_in[30], (const int*)d_in[31],
                       (const int*)d_in[32], (const int*)d_in[33]};

  int*   wsi = (int*)d_ws;
  float* wsf = (float*)d_ws;
  unsigned short* wsu = (unsigned short*)d_ws;

  // ---- workspace layout (r10/r11-proven chain, unchanged) ----
  const int CNT = 0, CUR = 5120, OFS = 10240, SCL = 15360;
  static const int PT[5]   = {20480, 20992, 23040, 31232, 64000};          // end 195072
  const int CI20 = 195072, CI31 = 203264, CI30 = 236032;
  const int CI42 = 268800, CI41 = 399872, CI40 = 530944;                   // end 662016 (contiguous)
  static const int SG01[2] = {662016, 1186304};                            // fp32 seg lvl0/1, end 2103808
  static const int PPu[5]  = {0, 0, 4207616, 6435840, 8860672};            // bf16 partials, end 13906944
  static const int SBu[5]  = {13906944, 14431232, 15348736, 16462848, 17708032}; // end 19018752 (38.04 MB)
  static const int WTu[5]  = {1324032, 1717248, 2405376, 3240960, 4174848};// over SG01/PP2-head (conv_wtt->gemm)
  const int PROJ = 2578944;                                                // f32 over PP2-tail/PP3/PP4 (gemm->ln)

  hipMemsetAsync(wsi + CNT, 0, (size_t)10240 * 4, stream);   // cnt + cur only

  PreArgs pa{inv[1], inv[2], inv[3], inv[4],
             wsi + CI20, wsi + CI31, wsi + CI30, wsi + CI42, wsi + CI41, wsi + CI40,
             {}, wsi + CNT};
  for (int i = 0; i < 5; i++) pa.p2s[i] = p2s[i];
  pre_k<<<1354, 256, 0, stream>>>(pa);

  scan_k<<<10, 512, 0, stream>>>(wsi + CNT, wsi + OFS, wsf + SCL);

  ScArgs sc{};
  for (int i = 0; i < 5; i++) { sc.p2s[i] = p2s[i]; sc.pt[i] = wsi + PT[i]; }
  sc.cur = wsi + CUR; sc.off = wsi + OFS;
  scat_all_k<<<682, 256, 0, stream>>>(sc);

  const int* cimap[5][5] = {};
  cimap[1][0] = inv[1];
  cimap[2][1] = inv[2]; cimap[2][0] = wsi + CI20;
  cimap[3][2] = inv[3]; cimap[3][1] = wsi + CI31; cimap[3][0] = wsi + CI30;
  cimap[4][3] = inv[4]; cimap[4][2] = wsi + CI42; cimap[4][1] = wsi + CI41; cimap[4][0] = wsi + CI40;

  int offs[5][5] = {};
  for (int i = 1; i < 5; i++)
    for (int j = i - 1; j >= 0; j--) offs[i][j] = CN_[i] + offs[i - 1][j];

  RedAll ra{};
  for (int i = 0; i < 5; i++) {
    int d = 0;
    for (int j = i; j >= 0; j--) {
      ra.x[i][d]      = x[j];
      ra.ci[i][d]     = (j == i) ? nullptr : cimap[i][j];
      ra.Njl[i][d]    = N_[j];
      ra.CN[i][d]     = CN_[j];
      ra.colOFF[i][d] = offs[i][j];
      d++;
    }
    ra.nb[i] = d; ra.N[i] = N_[i]; ra.CF[i] = CF_[i]; ra.nchunk[i] = NC_[i];
    ra.pt[i] = wsi + PT[i]; ra.cnt[i] = wsi + CNT + i * 1024;
    ra.segoff[i] = wsi + OFS + i * 1024;
    ra.part[i] = (i >= 2) ? (wsu + PPu[i]) : nullptr;
  }
  ra.seg01[0] = wsf + SG01[0]; ra.seg01[1] = wsf + SG01[1];
  reduce3_k<<<22528, 256, 0, stream>>>(ra);

  CsArgs ca{};
  ca.sg[0] = wsf + SG01[0]; ca.sg[1] = wsf + SG01[1];
  for (int i = 0; i < 5; i++) {
    ca.pp[i] = (i >= 2) ? (wsu + PPu[i]) : nullptr;
    ca.sb[i] = wsu + SBu[i];
    ca.CF[i] = CF_[i]; ca.KP[i] = KP_[i]; ca.NC[i] = NC_[i];
  }
  ca.scl = wsf + SCL;
  conv_seg_k<<<5120, 256, 0, stream>>>(ca);

  CwArgs cw{};
  for (int i = 0; i < 5; i++) { cw.w[i] = W[i]; cw.wt[i] = wsu + WTu[i]; cw.CF[i] = CF_[i]; cw.KP[i] = KP_[i]; }
  conv_wtt_k<<<dim3(240, 5), 256, 0, stream>>>(cw);

  G2Args ga{};
  for (int i = 0; i < 5; i++) {
    ga.sb[i] = wsu + SBu[i]; ga.wt[i] = wsu + WTu[i]; ga.bias[i] = bias[i];
    ga.KP[i] = KP_[i]; ga.KIT[i] = KP_[i] >> 6;
  }
  ga.proj = wsf + PROJ;
  gemm2_k<<<dim3(12, 8, 5), 256, 0, stream>>>(ga);

  LnArgs la{};
  for (int i = 0; i < 5; i++) { la.g[i] = g[i]; la.be[i] = be[i]; }
  ln_k<<<5120, 256, 0, stream>>>(la, wsf + PROJ, (float*)d_out);
}

// Round 13
// 171.707 us; speedup vs baseline: 1.1899x; 1.1899x over previous
//
#include <hip/hip_runtime.h>
#include <hip/hip_bf16.h>

#define NSEG 512
#define HID 768

typedef __attribute__((ext_vector_type(8))) short s16x8;
typedef __attribute__((ext_vector_type(8))) unsigned short u16x8;
typedef __attribute__((ext_vector_type(4))) unsigned short u16x4;
typedef __attribute__((ext_vector_type(4))) float f32x4;

__device__ __forceinline__ unsigned short f2bf(float x) {
  unsigned u = __builtin_bit_cast(unsigned, x);
  unsigned r = (u + 0x7fff + ((u >> 16) & 1)) >> 16;   // RNE
  return (unsigned short)r;
}

__device__ __forceinline__ float bf2f(unsigned short h) {
  unsigned u = ((unsigned)h) << 16;
  return __builtin_bit_cast(float, u);
}

__device__ __forceinline__ void gl_lds16(const void* g, void* l) {
  __builtin_amdgcn_global_load_lds(
      (const __attribute__((address_space(1))) unsigned*)g,
      (__attribute__((address_space(3))) unsigned*)l, 16, 0, 0);
}

// ---------------- fused compose (all chains) + histogram (all levels) ----------------
struct PreArgs {
  const int *inv1, *inv2, *inv3, *inv4;
  int *c20, *c31, *c30, *c42, *c41, *c40;
  const int* p2s[5];
  int* cnt;
};

__device__ __forceinline__ bool lvl_decode(int t, int& lvl, int& u, int& N) {
  if      (t < 512)    { lvl = 0; u = t;          N = 256; }
  else if (t < 2560)   { lvl = 1; u = t - 512;    N = 1024; }
  else if (t < 10752)  { lvl = 2; u = t - 2560;   N = 4096; }
  else if (t < 43520)  { lvl = 3; u = t - 10752;  N = 16384; }
  else if (t < 174592) { lvl = 4; u = t - 43520;  N = 65536; }
  else return false;
  return true;
}

__global__ __launch_bounds__(256)
void pre_k(PreArgs a) {
  int t = blockIdx.x * 256 + threadIdx.x;
  if (t < 8192) {
    int b = (t >= 4096);
    a.c20[t] = a.inv1[b * 1024 + a.inv2[t]];
  } else if (t < 40960) {
    int u = t - 8192;
    int b = (u >= 16384);
    int n2 = a.inv3[u];
    int n1 = a.inv2[b * 4096 + n2]; a.c31[u] = n1;
    a.c30[u] = a.inv1[b * 1024 + n1];
  } else if (t < 172032) {
    int u = t - 40960;
    int b = (u >= 65536);
    int n3 = a.inv4[u];
    int n2 = a.inv3[b * 16384 + n3]; a.c42[u] = n2;
    int n1 = a.inv2[b * 4096 + n2];  a.c41[u] = n1;
    a.c40[u] = a.inv1[b * 1024 + n1];
  } else {
    int u0 = t - 172032;
    int lvl, u, N;
    if (!lvl_decode(u0, lvl, u, N)) return;
    int b = (u >= N);
    atomicAdd(&a.cnt[lvl * 1024 + b * NSEG + a.p2s[lvl][u]], 1);
  }
}

// ---------------- scan + 1/m ----------------
__global__ __launch_bounds__(512)
void scan_k(const int* __restrict__ cnt, int* __restrict__ off, float* __restrict__ scl) {
  __shared__ int sm[NSEG];
  int base = blockIdx.x * NSEG;
  int t = threadIdx.x;
  int v = cnt[base + t];
  sm[t] = v;
  __syncthreads();
  for (int d = 1; d < NSEG; d <<= 1) {
    int u = (t >= d) ? sm[t - d] : 0;
    __syncthreads();
    sm[t] += u;
    __syncthreads();
  }
  off[base + t] = sm[t] - v;
  scl[base + t] = 1.0f / (float)(v > 0 ? v : 1);
}

// ---------------- fused scatter (all levels) ----------------
struct ScArgs { const int* p2s[5]; int* pt[5]; int* cur; const int* off; };

__global__ __launch_bounds__(256)
void scat_all_k(ScArgs a) {
  int t = blockIdx.x * 256 + threadIdx.x;
  int lvl, u, N;
  if (!lvl_decode(t, lvl, u, N)) return;
  int b = (u >= N);
  int n = u - b * N;
  int idx = lvl * 1024 + b * NSEG + a.p2s[lvl][u];
  int pos = a.off[idx] + atomicAdd(&a.cur[idx], 1);
  a.pt[lvl][b * N + pos] = n;
}

// ---------------- mega reduce: all levels, one launch, fp32 gathers ----------------
// lvl0/1: writes scaled+swizzled bf16 DIRECTLY into SB (KP==CF there).
// lvl2-4: chunked bf16 partials (combined later).
struct RedAll {
  const float* x[5][5];
  const int*   ci[5][5];
  int Njl[5][5], CN[5][5], colOFF[5][5];
  int nb[5], N[5], CF[5], nchunk[5];
  const int* pt[5]; const int* cnt[5]; const int* segoff[5];
  unsigned short* sb01[2];
  const float* scl;
  unsigned short* part[5];
};

__global__ __launch_bounds__(256)
void reduce3_k(RedAll A) {
  int gb = blockIdx.x;
  int lvl, lb;
  if      (gb < 1024) { lvl = 0; lb = gb; }
  else if (gb < 2048) { lvl = 1; lb = gb - 1024; }
  else if (gb < 4096) { lvl = 2; lb = gb - 2048; }
  else if (gb < 6144) { lvl = 3; lb = gb - 4096; }
  else                { lvl = 4; lb = gb - 6144; }
  int chunk = lb >> 10;
  int bs    = lb & 1023;
  int b     = bs >> 9;
  int t     = threadIdx.x;
  int m     = A.cnt[lvl][bs];
  int CF    = A.CF[lvl];
  int nb    = A.nb[lvl];
  int N     = A.N[lvl];

  const float* xs[2]; const int* cim[2]; int str[2]; bool val[2];
#pragma unroll
  for (int k = 0; k < 2; k++) {
    int c4 = (t + k * 256) * 4;
    val[k] = c4 < CF;
    xs[k] = nullptr; cim[k] = nullptr; str[k] = 1;
    if (val[k]) {
      int j = 0;
      while (j < nb - 1 && !(c4 >= A.colOFF[lvl][j] && c4 < A.colOFF[lvl][j] + A.CN[lvl][j])) j++;
      xs[k]  = A.x[lvl][j] + (size_t)b * A.Njl[lvl][j] * A.CN[lvl][j] + (c4 - A.colOFF[lvl][j]);
      cim[k] = A.ci[lvl][j] ? (A.ci[lvl][j] + (size_t)b * N) : nullptr;
      str[k] = A.CN[lvl][j];
    }
  }

  bool direct = (lvl <= 1);
  int start = 0, end = m;
  if (!direct) {
    int nch = A.nchunk[lvl];
    int cs = (m + nch - 1) / nch;
    start = chunk * cs;
    end = min(m, start + cs);
  }
  // direct + m==0 falls through: loop skipped, writes scaled zeros.

  float ax[2][4] = {};
  if (start < end) {
    const int* pl = A.pt[lvl] + (size_t)b * N + A.segoff[lvl][bs];
    int p = start;
    for (; p + 8 <= end; p += 8) {
      int n[8];
#pragma unroll
      for (int q = 0; q < 8; q++) n[q] = pl[p + q];
#pragma unroll
      for (int k = 0; k < 2; k++) if (val[k]) {
        int r[8];
#pragma unroll
        for (int q = 0; q < 8; q++) r[q] = cim[k] ? cim[k][n[q]] : n[q];
        float4 v[8];
#pragma unroll
        for (int q = 0; q < 8; q++) v[q] = *(const float4*)(xs[k] + (size_t)r[q] * str[k]);
#pragma unroll
        for (int q = 0; q < 8; q++) {
          ax[k][0] += v[q].x; ax[k][1] += v[q].y; ax[k][2] += v[q].z; ax[k][3] += v[q].w;
        }
      }
    }
    for (; p < end; p++) {
      int n0 = pl[p];
#pragma unroll
      for (int k = 0; k < 2; k++) if (val[k]) {
        int r0 = cim[k] ? cim[k][n0] : n0;
        float4 v0 = *(const float4*)(xs[k] + (size_t)r0 * str[k]);
        ax[k][0] += v0.x; ax[k][1] += v0.y; ax[k][2] += v0.z; ax[k][3] += v0.w;
      }
    }
  }

  if (direct) {
    // scaled + swizzled bf16 direct to SB. group g -> orig chunk co=g>>1, half=g&1;
    // stored chunk c_st = kb*8 + (w0 ^ (rl&7)); KP == CF for lvl 0/1.
    float s = A.scl[lvl * 1024 + bs];
    unsigned short* sbp = A.sb01[lvl];
#pragma unroll
    for (int k = 0; k < 2; k++) if (val[k]) {
      int g = t + k * 256;
      int co = g >> 1, half = g & 1;
      int kb = co >> 3, w0 = co & 7;
      int c_st = kb * 8 + (w0 ^ (bs & 7));
      u16x4 o = {f2bf(ax[k][0] * s), f2bf(ax[k][1] * s), f2bf(ax[k][2] * s), f2bf(ax[k][3] * s)};
      *(u16x4*)(sbp + (size_t)bs * CF + c_st * 8 + half * 4) = o;
    }
  } else {
    unsigned short* po = A.part[lvl] + ((size_t)chunk * 1024 + bs) * CF;
#pragma unroll
    for (int k = 0; k < 2; k++) if (val[k]) {
      int c4 = (t + k * 256) * 4;
      u16x4 o = {f2bf(ax[k][0]), f2bf(ax[k][1]), f2bf(ax[k][2]), f2bf(ax[k][3])};
      *(u16x4*)(po + c4) = o;
    }
  }
}

// ---------------- merged: combine partials (lvl2-4) + W transpose, one launch ----------------
// blocks [0,3072): conv_seg lvl2-4.  [3072,4272): conv_wtt tiles.
struct CvArgs {
  const unsigned short* pp[5];
  unsigned short* sb[5];
  const float* scl;
  int CF[5]; int KP[5]; int NC[5];
  const float* w[5];
  unsigned short* wt[5];
};

__global__ __launch_bounds__(256)
void conv_all_k(CvArgs a) {
  __shared__ float lds[64][65];
  int blk = blockIdx.x;
  int t = threadIdx.x;

  if (blk < 3072) {
    int lvl = 2 + (blk >> 10);
    int rl  = blk & 1023;
    int CF = a.CF[lvl], KP = a.KP[lvl];
    int c = t;
    if (c >= (KP >> 3)) return;
    float s = a.scl[lvl * 1024 + rl];
    int w = c & 7, kb = c >> 3;
    int k0 = kb * 64 + ((w ^ (rl & 7)) << 3);
    u16x8 o = {0, 0, 0, 0, 0, 0, 0, 0};
    if (k0 < CF) {
      float acc[8] = {};
      int nc = a.NC[lvl];
      const unsigned short* base = a.pp[lvl] + (size_t)rl * CF + k0;
      for (int n = 0; n < nc; n++) {
        u16x8 v = *(const u16x8*)(base + (size_t)n * 1024 * CF);
#pragma unroll
        for (int e = 0; e < 8; e++) acc[e] += bf2f(v[e]);
      }
#pragma unroll
      for (int e = 0; e < 8; e++) o[e] = f2bf(acc[e] * s);
    }
    *(u16x8*)(a.sb[lvl] + (size_t)rl * KP + c * 8) = o;
    return;
  }

  int idx = blk - 3072;
  int lvl = idx / 240;
  int tile = idx - lvl * 240;
  int KP = a.KP[lvl], CF = a.CF[lvl];
  int ntiles = 12 * (KP >> 6);
  if (tile >= ntiles) return;
  int kb  = tile / 12;
  int nb0 = tile - kb * 12;

  const float* wsrc = a.w[lvl];
#pragma unroll
  for (int e = 0; e < 4; e++) {
    int f = e * 256 + t;
    int row = f >> 4;
    int c4  = (f & 15) * 4;
    int k = kb * 64 + row;
    float4 v = make_float4(0.f, 0.f, 0.f, 0.f);
    if (k < CF) v = *(const float4*)(wsrc + (size_t)k * HID + nb0 * 64 + c4);
    lds[row][c4 + 0] = v.x; lds[row][c4 + 1] = v.y;
    lds[row][c4 + 2] = v.z; lds[row][c4 + 3] = v.w;
  }
  __syncthreads();

  unsigned short* wt = a.wt[lvl];
#pragma unroll
  for (int h = 0; h < 2; h++) {
    int idx2 = h * 256 + t;
    int n_loc = idx2 >> 3;
    int w2    = idx2 & 7;
    int kbase = (w2 ^ (n_loc & 7)) << 3;
    u16x8 o;
#pragma unroll
    for (int e = 0; e < 8; e++) o[e] = f2bf(lds[kbase + e][n_loc]);
    int n = nb0 * 64 + n_loc;
    *(u16x8*)(wt + (size_t)n * KP + kb * 64 + w2 * 8) = o;
  }
}

// ---------------- bf16 MFMA GEMM: proj = segbf @ Wt^T + bias ----------------
struct G2Args {
  const unsigned short* sb[5];
  const unsigned short* wt[5];
  const float* bias[5];
  float* proj;
  int KP[5];
  int KIT[5];
};

__global__ __launch_bounds__(256)
void gemm2_k(G2Args g) {
  int lvl = blockIdx.z;
  int n0 = blockIdx.x * 64;
  int m0 = blockIdx.y * 128;
  const char* A = (const char*)g.sb[lvl];
  const char* Bw = (const char*)g.wt[lvl];
  int KP = g.KP[lvl];
  int KIT = g.KIT[lvl];

  __shared__ char smem[49152];

  int t = threadIdx.x;
  int lane = t & 63;
  int w = t >> 6;
  int wm = w >> 1, wn = w & 1;

  f32x4 acc[4][2] = {};

  int rowb = t >> 3;
  int colb = (t & 7) * 16;

  auto stg = [&](int buf, int it) {
    char* base = smem + buf * 24576;
#pragma unroll
    for (int j = 0; j < 4; j++) {
      int row = j * 32 + rowb;
      gl_lds16(A + (size_t)(m0 + row) * (KP * 2) + it * 128 + colb,
               base + j * 4096 + t * 16);
    }
#pragma unroll
    for (int j = 0; j < 2; j++) {
      int row = j * 32 + rowb;
      gl_lds16(Bw + (size_t)(n0 + row) * (KP * 2) + it * 128 + colb,
               base + 16384 + j * 4096 + t * 16);
    }
  };

  int r15 = lane & 15, hi = lane >> 4, sx = (lane & 7) << 4;

  stg(0, 0);
  int cur = 0;
  for (int it = 0; it < KIT; ++it) {
    __syncthreads();
    if (it + 1 < KIT) stg(cur ^ 1, it + 1);
    const char* base = smem + cur * 24576;
    s16x8 af[2][4]; s16x8 bf2v[2][2];
#pragma unroll
    for (int s = 0; s < 2; s++) {
      int cb = (s * 64 + hi * 16) ^ sx;
#pragma unroll
      for (int fm = 0; fm < 4; fm++) {
        int row = wm * 64 + fm * 16 + r15;
        af[s][fm] = *(const s16x8*)(base + row * 128 + cb);
      }
#pragma unroll
      for (int fn = 0; fn < 2; fn++) {
        int row = wn * 32 + fn * 16 + r15;
        bf2v[s][fn] = *(const s16x8*)(base + 16384 + row * 128 + cb);
      }
    }
#pragma unroll
    for (int s = 0; s < 2; s++)
#pragma unroll
      for (int fm = 0; fm < 4; fm++)
#pragma unroll
        for (int fn = 0; fn < 2; fn++)
          acc[fm][fn] = __builtin_amdgcn_mfma_f32_16x16x32_bf16(af[s][fm], bf2v[s][fn], acc[fm][fn], 0, 0, 0);
    cur ^= 1;
  }

  const float* bias = g.bias[lvl];
  float* proj = g.proj + ((size_t)lvl * 1024 + m0) * HID;
#pragma unroll
  for (int fm = 0; fm < 4; fm++)
#pragma unroll
    for (int fn = 0; fn < 2; fn++) {
      int col = n0 + wn * 32 + fn * 16 + r15;
      int rb = wm * 64 + fm * 16 + hi * 4;
      float bi = bias[col];
      f32x4 v = acc[fm][fn];
#pragma unroll
      for (int r = 0; r < 4; r++)
        proj[(size_t)(rb + r) * HID + col] = v[r] + bi;
    }
}

// ---------------- LayerNorm over HID=768 (fp32 in/out) ----------------
struct LnArgs { const float* g[5]; const float* be[5]; };

__global__ __launch_bounds__(256)
void ln_k(LnArgs la, const float* __restrict__ proj, float* __restrict__ out) {
  int row = blockIdx.x;
  int lvl = row >> 10;
  const float* x = proj + (size_t)row * HID;
  int t = threadIdx.x;
  float v0 = x[t], v1 = x[t + 256], v2 = x[t + 512];
  float s = v0 + v1 + v2;
  float q = v0 * v0 + v1 * v1 + v2 * v2;
#pragma unroll
  for (int d = 32; d >= 1; d >>= 1) { s += __shfl_down(s, d); q += __shfl_down(q, d); }
  __shared__ float ps[4], pq[4];
  int w = t >> 6;
  if ((t & 63) == 0) { ps[w] = s; pq[w] = q; }
  __syncthreads();
  float S = ps[0] + ps[1] + ps[2] + ps[3];
  float Q = pq[0] + pq[1] + pq[2] + pq[3];
  float mean = S * (1.0f / HID);
  float var  = Q * (1.0f / HID) - mean * mean;
  float rs   = rsqrtf(var + 1e-5f);
  const float* g  = la.g[lvl];
  const float* be = la.be[lvl];
  float* o = out + (size_t)row * HID;
  o[t]       = (v0 - mean) * rs * g[t]       + be[t];
  o[t + 256] = (v1 - mean) * rs * g[t + 256] + be[t + 256];
  o[t + 512] = (v2 - mean) * rs * g[t + 512] + be[t + 512];
}

// =====================================================================
extern "C" void kernel_launch(void* const* d_in, const int* in_sizes, int n_in,
                              void* d_out, int out_size, void* d_ws, size_t ws_size,
                              hipStream_t stream) {
  static const int N_[5]  = {256, 1024, 4096, 16384, 65536};
  static const int CN_[5] = {512, 384, 192, 96, 48};
  static const int CF_[5] = {512, 896, 1088, 1184, 1232};
  static const int KP_[5] = {512, 896, 1088, 1216, 1280};   // CF rounded to 64
  static const int NC_[5] = {1, 1, 2, 2, 4};                // point-chunks (no atomics)

  const float* x[5]; const int* p2s[5]; const float* W[5];
  const float* bias[5]; const float* g[5]; const float* be[5];
  for (int i = 0; i < 5; i++) {
    x[i]    = (const float*)d_in[6 * i + 0];
    p2s[i]  = (const int*)  d_in[6 * i + 1];
    W[i]    = (const float*)d_in[6 * i + 2];
    bias[i] = (const float*)d_in[6 * i + 3];
    g[i]    = (const float*)d_in[6 * i + 4];
    be[i]   = (const float*)d_in[6 * i + 5];
  }
  const int* inv[5] = {nullptr, (const int*)d_in[30], (const int*)d_in[31],
                       (const int*)d_in[32], (const int*)d_in[33]};

  int*   wsi = (int*)d_ws;
  float* wsf = (float*)d_ws;
  unsigned short* wsu = (unsigned short*)d_ws;

  // ---- workspace layout ----
  // f32-slot offsets:
  const int CNT = 0, CUR = 5120, OFS = 10240, SCL = 15360;
  static const int PT[5]   = {20480, 20992, 23040, 31232, 64000};          // end 195072
  const int CI20 = 195072, CI31 = 203264, CI30 = 236032;
  const int CI42 = 268800, CI41 = 399872, CI40 = 530944;                   // end 662016 (contiguous)
  // u16 offsets:
  static const int PPu[5]  = {0, 0, 4207616, 6435840, 8860672};            // bf16 partials lvl2-4, end 13906944
  static const int SBu[5]  = {13906944, 14431232, 15348736, 16462848, 17708032}; // end 19018752 (38.04 MB proven)
  // WT relocated over dead PT/CI/old-SG01 space (live conv_all -> gemm):
  static const int WTu[5]  = {40960, 434176, 1122304, 1957888, 2891776};   // end 3874816 < PPu[2]
  const int PROJ = 2578944;  // f32 over dead PP region (u16 5157888..13022208), live gemm->ln

  hipMemsetAsync(wsi + CNT, 0, (size_t)10240 * 4, stream);   // cnt + cur only

  PreArgs pa{inv[1], inv[2], inv[3], inv[4],
             wsi + CI20, wsi + CI31, wsi + CI30, wsi + CI42, wsi + CI41, wsi + CI40,
             {}, wsi + CNT};
  for (int i = 0; i < 5; i++) pa.p2s[i] = p2s[i];
  pre_k<<<1354, 256, 0, stream>>>(pa);

  scan_k<<<10, 512, 0, stream>>>(wsi + CNT, wsi + OFS, wsf + SCL);

  ScArgs sc{};
  for (int i = 0; i < 5; i++) { sc.p2s[i] = p2s[i]; sc.pt[i] = wsi + PT[i]; }
  sc.cur = wsi + CUR; sc.off = wsi + OFS;
  scat_all_k<<<682, 256, 0, stream>>>(sc);

  const int* cimap[5][5] = {};
  cimap[1][0] = inv[1];
  cimap[2][1] = inv[2]; cimap[2][0] = wsi + CI20;
  cimap[3][2] = inv[3]; cimap[3][1] = wsi + CI31; cimap[3][0] = wsi + CI30;
  cimap[4][3] = inv[4]; cimap[4][2] = wsi + CI42; cimap[4][1] = wsi + CI41; cimap[4][0] = wsi + CI40;

  int offs[5][5] = {};
  for (int i = 1; i < 5; i++)
    for (int j = i - 1; j >= 0; j--) offs[i][j] = CN_[i] + offs[i - 1][j];

  RedAll ra{};
  for (int i = 0; i < 5; i++) {
    int d = 0;
    for (int j = i; j >= 0; j--) {
      ra.x[i][d]      = x[j];
      ra.ci[i][d]     = (j == i) ? nullptr : cimap[i][j];
      ra.Njl[i][d]    = N_[j];
      ra.CN[i][d]     = CN_[j];
      ra.colOFF[i][d] = offs[i][j];
      d++;
    }
    ra.nb[i] = d; ra.N[i] = N_[i]; ra.CF[i] = CF_[i]; ra.nchunk[i] = NC_[i];
    ra.pt[i] = wsi + PT[i]; ra.cnt[i] = wsi + CNT + i * 1024;
    ra.segoff[i] = wsi + OFS + i * 1024;
    ra.part[i] = (i >= 2) ? (wsu + PPu[i]) : nullptr;
  }
  ra.sb01[0] = wsu + SBu[0]; ra.sb01[1] = wsu + SBu[1];
  ra.scl = wsf + SCL;
  reduce3_k<<<10240, 256, 0, stream>>>(ra);

  // merged: partial-combine (lvl2-4 -> SB) + W transpose (-> WT over dead PT/CI)
  CvArgs cv{};
  for (int i = 0; i < 5; i++) {
    cv.pp[i] = (i >= 2) ? (wsu + PPu[i]) : nullptr;
    cv.sb[i] = wsu + SBu[i];
    cv.CF[i] = CF_[i]; cv.KP[i] = KP_[i]; cv.NC[i] = NC_[i];
    cv.w[i] = W[i]; cv.wt[i] = wsu + WTu[i];
  }
  cv.scl = wsf + SCL;
  conv_all_k<<<4272, 256, 0, stream>>>(cv);

  G2Args ga{};
  for (int i = 0; i < 5; i++) {
    ga.sb[i] = wsu + SBu[i]; ga.wt[i] = wsu + WTu[i]; ga.bias[i] = bias[i];
    ga.KP[i] = KP_[i]; ga.KIT[i] = KP_[i] >> 6;
  }
  ga.proj = wsf + PROJ;
  gemm2_k<<<dim3(12, 8, 5), 256, 0, stream>>>(ga);

  LnArgs la{};
  for (int i = 0; i < 5; i++) { la.g[i] = g[i]; la.be[i] = be[i]; }
  ln_k<<<5120, 256, 0, stream>>>(la, wsf + PROJ, (float*)d_out);
}